// Round 1
// baseline (7641.039 us; speedup 1.0000x reference)
//
#include <hip/hip_runtime.h>
#include <stdint.h>
#include <math.h>

#define T 4096
#define NTAGS 6
#define START_TAG 3
#define STOP_TAG 4
#define NEGV -10000.0f
#define FLAG_MAGIC 0x5A000000u

// ---------------------------------------------------------------------------
// K0: transpose w_ih (both dirs) into wT[k][col], col = d*1024+g; combined bias
// ---------------------------------------------------------------------------
__global__ __launch_bounds__(256) void k0_prep(
    const float* __restrict__ wf, const float* __restrict__ wb,
    const float* __restrict__ bif, const float* __restrict__ bhf,
    const float* __restrict__ bib, const float* __restrict__ bhb,
    float* __restrict__ wT, float* __restrict__ bias2) {
  int idx = blockIdx.x * 256 + threadIdx.x;   // 0 .. 524287
  int k = idx >> 11, col = idx & 2047;
  int d = col >> 10, g = col & 1023;
  const float* w = d ? wb : wf;
  wT[idx] = w[g * 256 + k];                   // wT[k*2048 + col]
  if (idx < 2048) bias2[idx] = d ? (bib[g] + bhb[g]) : (bif[g] + bhf[g]);
}

// ---------------------------------------------------------------------------
// K1: zpre[d][t][g] = emb[sent[t]] . w_ih[d][g] + b_ih + b_hh
// ---------------------------------------------------------------------------
__global__ __launch_bounds__(256) void k1_zpre(
    const int* __restrict__ sent, const float* __restrict__ emb,
    const float* __restrict__ wT, const float* __restrict__ bias2,
    float* __restrict__ zpre) {
  int tb = blockIdx.x, cb = blockIdx.y;
  int tid = threadIdx.x;
  int col = cb * 256 + tid;
  int d = col >> 10, g = col & 1023;
  __shared__ float xs[32 * 256];
  int t0 = tb * 32;
  for (int r = 0; r < 32; r++) {
    int s = sent[t0 + r];                       // uniform -> scalar broadcast
    xs[r * 256 + tid] = emb[(size_t)s * 256 + tid];
  }
  __syncthreads();
  float acc[32];
#pragma unroll
  for (int r = 0; r < 32; r++) acc[r] = 0.f;
  const float4* xs4 = (const float4*)xs;
  for (int kq = 0; kq < 64; kq++) {
    float w0 = wT[(4 * kq + 0) * 2048 + col];
    float w1 = wT[(4 * kq + 1) * 2048 + col];
    float w2 = wT[(4 * kq + 2) * 2048 + col];
    float w3 = wT[(4 * kq + 3) * 2048 + col];
#pragma unroll
    for (int r = 0; r < 32; r++) {
      float4 x4 = xs4[r * 64 + kq];             // uniform address -> broadcast
      acc[r] += w0 * x4.x + w1 * x4.y + w2 * x4.z + w3 * x4.w;
    }
  }
  float bb = bias2[col];
  for (int r = 0; r < 32; r++)
    zpre[((size_t)d * T + (t0 + r)) * 1024 + g] = acc[r] + bb;
}

// ---------------------------------------------------------------------------
// K2: sequential BiLSTM recurrence. 8 WGs (= d*4+wg), 1024 thr each.
// WG owns cells [64wg,64wg+64) -> 256 gate rows; 4 threads/row, 64 fp32
// weights/thread register-resident. Cross-CU h exchange + flags via
// AGENT-scope atomics (MALL coherent across XCDs). Flags are step-numbered
// exact-match values -> robust vs 0xAA ws poison.
// ---------------------------------------------------------------------------
__global__ __launch_bounds__(1024) void k2_lstm(
    const float* __restrict__ zpre,
    const float* __restrict__ whf, const float* __restrict__ whb,
    const float* __restrict__ h0, const float* __restrict__ c0,
    float* h_all, unsigned int* flags) {
  int bx = blockIdx.x;
  int d = bx >> 2, wg = bx & 3;
  const float* w_hh = d ? whb : whf;
  int tid = threadIdx.x;
  int row = tid >> 2, q = tid & 3;            // lanes 4r..4r+3 share row r
  int gate = row >> 6, cl = row & 63;         // 0=i,1=f,2=g,3=o
  int B = wg * 64;
  int g_row = gate * 256 + B + cl;

  float4 w4[16];                              // 64 weights, k in [64q,64q+64)
  {
    const float4* wp = (const float4*)(w_hh + (size_t)g_row * 256 + q * 64);
#pragma unroll
    for (int m = 0; m < 16; m++) w4[m] = wp[m];
  }
  // pitch 72 floats: 4 q-chunks' b128 broadcast reads hit disjoint bank quads
  __shared__ float h_pad[4 * 72];
  __shared__ float z_lds[256];
  __shared__ float zin[256];
  float c = 0.f;
  if (tid < 64) c = c0[d * 256 + B + tid];
  const float* zp_d = zpre + (size_t)d * T * 1024;
  float* h_d = h_all + (size_t)d * T * 256;
  unsigned int* flg = flags + d * T * 4;

  for (int s = 0; s < T; s++) {
    int t = d ? (T - 1 - s) : s;
    float zv = 0.f;                 // issue zpre load before the spin
    if (tid < 256) {
      int lg = tid >> 6, lc = tid & 63;
      zv = zp_d[(size_t)t * 1024 + lg * 256 + B + lc];
    }
    if (s == 0) {
      if (tid < 256) h_pad[(tid >> 6) * 72 + (tid & 63)] = h0[d * 256 + tid];
    } else {
      if (tid < 4) {
        unsigned int expv = FLAG_MAGIC + (unsigned)(s - 1);
        while (__hip_atomic_load(&flg[(s - 1) * 4 + tid], __ATOMIC_RELAXED,
                                 __HIP_MEMORY_SCOPE_AGENT) != expv) { }
      }
      __syncthreads();
      if (tid < 256) {
        int tprev = d ? (t + 1) : (t - 1);
        float hv = __hip_atomic_load(&h_d[(size_t)tprev * 256 + tid],
                                     __ATOMIC_RELAXED, __HIP_MEMORY_SCOPE_AGENT);
        h_pad[(tid >> 6) * 72 + (tid & 63)] = hv;
      }
    }
    if (tid < 256) zin[tid] = zv;
    __syncthreads();

    const float4* hp = (const float4*)(h_pad + q * 72);
    float acc = 0.f;
#pragma unroll
    for (int m = 0; m < 16; m++) {
      float4 h4 = hp[m];
      acc += w4[m].x * h4.x;
      acc += w4[m].y * h4.y;
      acc += w4[m].z * h4.z;
      acc += w4[m].w * h4.w;
    }
    acc += __shfl_xor(acc, 1);
    acc += __shfl_xor(acc, 2);
    if (q == 0) {
      float z = acc + zin[row];
      float a = (gate == 2) ? tanhf(z) : 1.f / (1.f + expf(-z));
      z_lds[row] = a;
    }
    __syncthreads();
    if (tid < 64) {
      float iA = z_lds[tid], fA = z_lds[64 + tid];
      float gA = z_lds[128 + tid], oA = z_lds[192 + tid];
      c = fA * c + iA * gA;
      float hv = oA * tanhf(c);
      __hip_atomic_store(&h_d[(size_t)t * 256 + B + tid], hv,
                         __ATOMIC_RELAXED, __HIP_MEMORY_SCOPE_AGENT);
    }
    __syncthreads();  // drains h stores (vmcnt) before flag publish
    if (tid == 0) {
      __hip_atomic_store(&flg[s * 4 + wg], FLAG_MAGIC + (unsigned)s,
                         __ATOMIC_RELAXED, __HIP_MEMORY_SCOPE_AGENT);
      if (s >= 2)  // self-clean: safe, all peers consumed flag s-2 by now
        __hip_atomic_store(&flg[(s - 2) * 4 + wg], 0u,
                           __ATOMIC_RELAXED, __HIP_MEMORY_SCOPE_AGENT);
    }
  }
}

// ---------------------------------------------------------------------------
// K3: feats[t][tag] = [hf[t]; hb[t]] . W_out[tag] + b_out[tag]
// ---------------------------------------------------------------------------
__global__ __launch_bounds__(64) void k3_feats(
    const float* __restrict__ h_all, const float* __restrict__ Wout,
    const float* __restrict__ bout, float* __restrict__ feats) {
  int t = blockIdx.x;
  int j = threadIdx.x;
  const float* hf = h_all + (size_t)t * 256;
  const float* hb = h_all + (size_t)T * 256 + (size_t)t * 256;
  float s[6];
#pragma unroll
  for (int g = 0; g < 6; g++) s[g] = 0.f;
#pragma unroll
  for (int m = 0; m < 4; m++) {
    float a = hf[j + 64 * m];
#pragma unroll
    for (int g = 0; g < 6; g++) s[g] += a * Wout[g * 512 + j + 64 * m];
  }
#pragma unroll
  for (int m = 0; m < 4; m++) {
    float b = hb[j + 64 * m];
#pragma unroll
    for (int g = 0; g < 6; g++) s[g] += b * Wout[g * 512 + 256 + j + 64 * m];
  }
#pragma unroll
  for (int g = 0; g < 6; g++) {
#pragma unroll
    for (int off = 32; off >= 1; off >>= 1) s[g] += __shfl_xor(s[g], off);
  }
  if (j < 6) feats[(size_t)t * 6 + j] = s[j] + bout[j];
}

// ---------------------------------------------------------------------------
// K4: Viterbi forward (serial, first-max argmax like jnp.argmax) + parallel
// backtrace via 6-entry map-composition suffix scan. Single wave.
// ---------------------------------------------------------------------------
__global__ __launch_bounds__(64) void k4_viterbi(
    const float* __restrict__ feats, const float* __restrict__ trans,
    float* __restrict__ out) {
  __shared__ unsigned char bp_lds[T * 8];
  __shared__ float fbuf[2][64 * 6];
  int lane = threadIdx.x;

  float tr[6];
#pragma unroll
  for (int f = 0; f < 6; f++) tr[f] = (lane < 6) ? trans[lane * 6 + f] : 0.f;
  float fv = (lane == START_TAG) ? 0.f : NEGV;

  for (int idx = lane; idx < 384; idx += 64) fbuf[0][idx] = feats[idx];

  for (int cch = 0; cch < 64; cch++) {
    float pf[6];
    if (cch + 1 < 64) {
#pragma unroll
      for (int m = 0; m < 6; m++)
        pf[m] = feats[(cch + 1) * 384 + lane + 64 * m];   // prefetch in regs
    }
    const float* fb = fbuf[cch & 1];
    for (int j = 0; j < 64; j++) {
      int t = cch * 64 + j;
      float best = -3.4e38f;
      int bi = 0;
#pragma unroll
      for (int f = 0; f < 6; f++) {
        float v = __shfl(fv, f) + tr[f];     // trans[to][from] + fv[from]
        if (v > best) { best = v; bi = f; }  // strict > => first max index
      }
      float nfv = best + fb[j * 6 + (lane < 6 ? lane : 0)];
      if (lane < 6) {
        fv = nfv;
        bp_lds[t * 8 + lane] = (unsigned char)bi;
      }
    }
    if (cch + 1 < 64) {
#pragma unroll
      for (int m = 0; m < 6; m++)
        fbuf[(cch + 1) & 1][lane + 64 * m] = pf[m];
    }
  }

  float term = (lane < 6) ? (fv + trans[STOP_TAG * 6 + lane]) : -3.4e38f;
  float bestv = -3.4e38f;
  int bestt = 0;
#pragma unroll
  for (int f = 0; f < 6; f++) {
    float v = __shfl(term, f);
    if (v > bestv) { bestv = v; bestt = f; }
  }
  if (lane == 0) out[0] = bestv;

  // backtrace: path[t] = S_t(best), S_t = M_{t+1} o ... o M_{T-1}
  unsigned int ident = 0;
#pragma unroll
  for (int i = 0; i < 6; i++) ident |= (unsigned)i << (3 * i);

  unsigned int p = ident;                 // P_L = M_{64L} o ... o M_{64L+63}
  int base = lane * 64;
  for (int j2 = 0; j2 < 64; j2++) {
    const unsigned int* bw = (const unsigned int*)&bp_lds[(base + j2) * 8];
    unsigned int lo = bw[0], hi = bw[1];
    unsigned int mw = (lo & 7) | (((lo >> 8) & 7) << 3) | (((lo >> 16) & 7) << 6)
                    | (((lo >> 24) & 7) << 9) | ((hi & 7) << 12)
                    | (((hi >> 8) & 7) << 15);
    unsigned int np = 0;
#pragma unroll
    for (int i = 0; i < 6; i++) {
      unsigned int b = (mw >> (3 * i)) & 7;
      np |= ((p >> (3 * b)) & 7) << (3 * i);   // p := p o M_t
    }
    p = np;
  }
  unsigned int suf = p;   // suffix scan: suf_L = P_L o ... o P_63
#pragma unroll
  for (int off = 1; off < 64; off <<= 1) {
    unsigned int other = __shfl_down(suf, off);
    if (lane + off < 64) {
      unsigned int ns = 0;
#pragma unroll
      for (int i = 0; i < 6; i++) {
        unsigned int b = (other >> (3 * i)) & 7;
        ns |= ((suf >> (3 * b)) & 7) << (3 * i);   // suf := suf o other
      }
      suf = ns;
    }
  }
  unsigned int tail = __shfl_down(suf, 1);     // Suf_{L+1}
  if (lane == 63) tail = ident;
  unsigned int cur = tail;                     // = S_{64L+63}
  for (int j2 = 63; j2 >= 0; j2--) {
    int t = base + j2;
    out[1 + t] = (float)((cur >> (3 * bestt)) & 7);
    const unsigned int* bw = (const unsigned int*)&bp_lds[t * 8];
    unsigned int lo = bw[0], hi = bw[1];
    unsigned int mw = (lo & 7) | (((lo >> 8) & 7) << 3) | (((lo >> 16) & 7) << 6)
                    | (((lo >> 24) & 7) << 9) | ((hi & 7) << 12)
                    | (((hi >> 8) & 7) << 15);
    unsigned int nc = 0;
#pragma unroll
    for (int i = 0; i < 6; i++) {
      unsigned int b = (cur >> (3 * i)) & 7;
      nc |= ((mw >> (3 * b)) & 7) << (3 * i);  // cur := M_t o cur
    }
    cur = nc;
  }
}

// ---------------------------------------------------------------------------
extern "C" void kernel_launch(void* const* d_in, const int* in_sizes, int n_in,
                              void* d_out, int out_size, void* d_ws, size_t ws_size,
                              hipStream_t stream) {
  const int*   sent  = (const int*)d_in[0];
  const float* emb   = (const float*)d_in[1];
  const float* wihf  = (const float*)d_in[2];
  const float* whhf  = (const float*)d_in[3];
  const float* bihf  = (const float*)d_in[4];
  const float* bhhf  = (const float*)d_in[5];
  const float* wihb  = (const float*)d_in[6];
  const float* whhb  = (const float*)d_in[7];
  const float* bihb  = (const float*)d_in[8];
  const float* bhhb  = (const float*)d_in[9];
  const float* Wout  = (const float*)d_in[10];
  const float* bout  = (const float*)d_in[11];
  const float* trans = (const float*)d_in[12];
  const float* h0    = (const float*)d_in[13];
  const float* c0    = (const float*)d_in[14];
  float* out = (float*)d_out;

  char* ws = (char*)d_ws;
  float*        zpre  = (float*)(ws + 0);               // 32 MiB
  float*        h_all = (float*)(ws + 33554432);        //  8 MiB
  float*        feats = (float*)(ws + 41943040);        // 96 KiB
  unsigned int* flags = (unsigned int*)(ws + 42041344); // 128 KiB
  float*        wT    = (float*)(ws + 42172416);        //  2 MiB
  float*        bias2 = (float*)(ws + 44269568);        //  8 KiB

  k0_prep<<<2048, 256, 0, stream>>>(wihf, wihb, bihf, bhhf, bihb, bhhb, wT, bias2);
  dim3 g1(128, 8);
  k1_zpre<<<g1, 256, 0, stream>>>(sent, emb, wT, bias2, zpre);
  k2_lstm<<<8, 1024, 0, stream>>>(zpre, whhf, whhb, h0, c0, h_all, flags);
  k3_feats<<<4096, 64, 0, stream>>>(h_all, Wout, bout, feats);
  k4_viterbi<<<1, 64, 0, stream>>>(feats, trans, out);
}